// Round 8
// baseline (191.258 us; speedup 1.0000x reference)
//
#include <hip/hip_runtime.h>
#include <stdint.h>

// Problem constants: B=2, S=2048, H=1024, NH=16, HD=64, K=1024
// Inputs FP32 -> one cvt pass to bf16 -> bf16 MFMA pipeline -> output FP32.

typedef __attribute__((ext_vector_type(8))) short short8;
typedef __attribute__((ext_vector_type(4))) float floatx4;
typedef __attribute__((ext_vector_type(4))) unsigned int uint4v;
typedef __attribute__((ext_vector_type(2))) unsigned int uint2v;

__device__ __forceinline__ unsigned short f2bf(float f) {          // RNE
    unsigned int u = __float_as_uint(f);
    unsigned int r = u + 0x7fffu + ((u >> 16) & 1u);
    return (unsigned short)(r >> 16);
}
// pack two fp32 -> bf16x2 dword
#if __has_builtin(__builtin_amdgcn_cvt_pk_bf16_f32)
__device__ __forceinline__ unsigned int pack_bf2(float lo, float hi) {
    auto v = __builtin_amdgcn_cvt_pk_bf16_f32(lo, hi);
    return __builtin_bit_cast(unsigned int, v);
}
#else
__device__ __forceinline__ unsigned int pack_bf2(float lo, float hi) {
    unsigned int a = __float_as_uint(lo) + 0x8000u;
    unsigned int b = __float_as_uint(hi) + 0x8000u;
    return __builtin_amdgcn_perm(b, a, 0x07060302u);
}
#endif

// raw exp2 (v_exp_f32) when available
#if __has_builtin(__builtin_amdgcn_exp2f)
#define EXP2(x) __builtin_amdgcn_exp2f(x)
#else
#define EXP2(x) exp2f(x)
#endif

// async global->LDS, 16B per lane. LDS dest: wave-uniform base + lane*16.
__device__ __forceinline__ void gl2lds16(const void* g, void* l) {
    __builtin_amdgcn_global_load_lds(
        (const __attribute__((address_space(1))) unsigned int*)g,
        (__attribute__((address_space(3))) unsigned int*)l, 16, 0, 0);
}

#define MFMA32(a, b, c) __builtin_amdgcn_mfma_f32_16x16x32_bf16((a), (b), (c), 0, 0, 0)

// ---------------------------------------------------------------------------
// One-pass prep: fp32->bf16 for hidden / w_qkv / w_out, plus mask transform
// m2 = mask*log2(e) - 10*log2(e) (fp32). Grid exactly 8196 x 256.
// ---------------------------------------------------------------------------
__global__ __launch_bounds__(256)
void cvt_all(const float* __restrict__ a, const float* __restrict__ b,
             const float* __restrict__ c, const float* __restrict__ mask,
             unsigned short* __restrict__ oa, unsigned short* __restrict__ ob,
             unsigned short* __restrict__ oc, float* __restrict__ m2b)
{
    int i = blockIdx.x * 256 + threadIdx.x;
    if (i >= 2097152) {                     // mask range: 1024 groups
        int off = i - 2097152;
        float4 v = *(const float4*)(mask + (size_t)off * 4);
        const float L2E = 1.44269504f, C2 = -14.4269504f;
        float4 w;
        w.x = fmaf(v.x, L2E, C2); w.y = fmaf(v.y, L2E, C2);
        w.z = fmaf(v.z, L2E, C2); w.w = fmaf(v.w, L2E, C2);
        *(float4*)(m2b + (size_t)off * 4) = w;
        return;
    }
    const float* src; unsigned short* dst; int off;
    if (i < 1048576)      { src = a; dst = oa; off = i; }
    else if (i < 1835008) { src = b; dst = ob; off = i - 1048576; }
    else                  { src = c; dst = oc; off = i - 1835008; }
    float4 v = *(const float4*)(src + (size_t)off * 4);
    uint2v w;
    w[0] = pack_bf2(v.x, v.y);
    w[1] = pack_bf2(v.z, v.w);
    *(uint2v*)(dst + (size_t)off * 4) = w;
}

// ---------------------------------------------------------------------------
// NT GEMM v3: C[M,N] = A[M,K]*B[N,K]^T, bf16 in, fp32 accum, K=1024.
// 128 x BN tile, BK=32, 4 waves (2x2) x (64 x BN/2).
// TRIPLE-buffered LDS + depth-2 prefetch + counted vmcnt:
//   round-7 PMC: dbuf/BK=64 was stall-bound (MfmaUtil 13%, all pipes <25%,
//   2 blocks/CU). BK=32 tri-buffer = 48KB LDS -> 3 blocks/CU (grid 768 is
//   EXACTLY 3/CU: fully resident, no tail) and stage(t) gets TWO compute
//   phases (~500cy) to land instead of one.
//   vmcnt ledger (per wave, NDMA=NA+NB per stage): prologue stages 0,1
//   (2*NDMA outstanding). Step t: barrier1 (buf[t+2] consumers done) ->
//   issue stage(t+2) -> vmcnt(2*NDMA) retires stage(t), keeps t+1,t+2 in
//   flight -> barrier2 (tile t visible block-wide) -> compute buf[t].
//   Tail: t=NSTEP-2 vmcnt(NDMA); t=NSTEP-1 vmcnt(0).
// LDS layout: 128B paired-row lines (2 M-rows x 64B per line), 8x16B slots
//   XOR-swizzled by (line&7) -> conflict-free ds_read_b128 (same geometry
//   as the verified BK=64 scheme). Stage side pre-swizzles the GLOBAL source
//   address; LDS dest stays linear (gl2lds requirement).
// MODE 0: scatter bf16 to q/k ([B,NH,S,HD]) + V^T ([B,NH,HD,S'])
//         S' key-interleaved within 32-groups:
//         k' = (k&~31) | ((k>>2)&3)<<3 | ((k>>4)&1)<<2 | (k&3).
//         q PRE-SCALED by 0.125*log2(e) so attn exp2's the raw MFMA out.
// MODE 1: fp32 store outf[m*N+n].
// ---------------------------------------------------------------------------
template<int MODE, int BN>
__global__ __launch_bounds__(256)
void gemm_nt(const unsigned short* __restrict__ A,
             const unsigned short* __restrict__ Bm,
             unsigned short* __restrict__ out0,
             unsigned short* __restrict__ out1,
             unsigned short* __restrict__ out2,
             float* __restrict__ outf,
             int N)
{
    constexpr int BUFB  = 8192 + BN * 64;        // bytes per buffer (A + B)
    constexpr int NSTEP = 32;                    // K / 32
    constexpr int NA    = 2;                     // A DMAs per wave per stage
    constexpr int NB    = BN / 64;               // B DMAs per wave per stage
    constexpr int BSL   = BN / 32;
    __shared__ unsigned char smem[3 * BUFB];
    const int K = 1024;
    const int tid  = threadIdx.x;
    const int wave = tid >> 6, lane = tid & 63;
    const int l15  = lane & 15, quad = lane >> 4;
    const int wm = wave >> 1, wn = wave & 1;

    int Lid = blockIdx.y * gridDim.x + blockIdx.x;
    int bm = (Lid & 7) * 4 + ((Lid >> 3) & 3);
    int bn = Lid >> 5;

    floatx4 acc[4][BSL];
#pragma unroll
    for (int i = 0; i < 4; i++)
#pragma unroll
        for (int j = 0; j < BSL; j++)
            acc[i][j] = floatx4{0.f, 0.f, 0.f, 0.f};

    // staging maps: chunk s (16B units) -> LDS line L = s>>3, slot p = s&7.
    // content q = p ^ (L&7): global (Mrow = L*2 + (q>>2), Kblk = q&3).
    int soffA[NA], soffB[NB];
#pragma unroll
    for (int l = 0; l < NA; l++) {
        int s = (wave * NA + l) * 64 + lane;
        int L = s >> 3, q = (s & 7) ^ (L & 7);
        soffA[l] = (L * 2 + (q >> 2)) * K + (q & 3) * 8;
    }
#pragma unroll
    for (int l = 0; l < NB; l++) {
        int s = (wave * NB + l) * 64 + lane;
        int L = s >> 3, q = (s & 7) ^ (L & 7);
        soffB[l] = (L * 2 + (q >> 2)) * K + (q & 3) * 8;
    }
    // read maps: row r, K-block quad -> line r>>1, slot (((r&1)<<2)|quad)^(line&7)
    int aoff[4], boff[BSL];
#pragma unroll
    for (int i = 0; i < 4; i++) {
        int r = wm * 64 + i * 16 + l15, L = r >> 1;
        aoff[i] = L * 128 + (((((r & 1) << 2) | quad) ^ (L & 7)) * 16);
    }
#pragma unroll
    for (int j = 0; j < BSL; j++) {
        int r = wn * (BN / 2) + j * 16 + l15, L = r >> 1;
        boff[j] = 8192 + L * 128 + (((((r & 1) << 2) | quad) ^ (L & 7)) * 16);
    }

    const unsigned short* Abase = A  + (size_t)(bm * 128) * K;
    const unsigned short* Bbase = Bm + (size_t)(bn * BN) * K;

    auto STAGE = [&](int u, int bufb) {
        const int k0 = u * 32;
#pragma unroll
        for (int l = 0; l < NA; l++)
            gl2lds16(Abase + (size_t)soffA[l] + k0, &smem[bufb + (wave * NA + l) * 1024]);
#pragma unroll
        for (int l = 0; l < NB; l++)
            gl2lds16(Bbase + (size_t)soffB[l] + k0, &smem[bufb + 8192 + (wave * NB + l) * 1024]);
    };

    // prologue: stages 0,1 into buffers 0,1
    STAGE(0, 0);
    STAGE(1, BUFB);

    int b0 = 0, b2 = 2;                          // compute buf, stage buf
    for (int t = 0; t < NSTEP; t++) {
        // barrier 1: all waves done computing step t-1 -> buf[b2] reusable
        asm volatile("" ::: "memory");
        __builtin_amdgcn_s_barrier();
        asm volatile("" ::: "memory");
        if (t + 2 < NSTEP) {
            STAGE(t + 2, b2 * BUFB);
            // retire stage(t); stages t+1,t+2 (2*NDMA) stay in flight
            if (BN == 128) asm volatile("s_waitcnt vmcnt(8)" ::: "memory");
            else           asm volatile("s_waitcnt vmcnt(6)" ::: "memory");
        } else if (t + 2 == NSTEP) {
            if (BN == 128) asm volatile("s_waitcnt vmcnt(4)" ::: "memory");
            else           asm volatile("s_waitcnt vmcnt(3)" ::: "memory");
        } else {
            asm volatile("s_waitcnt vmcnt(0)" ::: "memory");
        }
        // barrier 2: tile t visible block-wide
        __builtin_amdgcn_s_barrier();
        asm volatile("" ::: "memory");

        const int cb = b0 * BUFB;
        short8 af[4], bfr[BSL];
#pragma unroll
        for (int i = 0; i < 4; i++)
            af[i] = *(const short8*)(&smem[cb + aoff[i]]);
#pragma unroll
        for (int j = 0; j < BSL; j++)
            bfr[j] = *(const short8*)(&smem[cb + boff[j]]);
#pragma unroll
        for (int i = 0; i < 4; i++)
#pragma unroll
            for (int j = 0; j < BSL; j++)
                acc[i][j] = MFMA32(af[i], bfr[j], acc[i][j]);

        b0 = (b0 == 2) ? 0 : b0 + 1;
        b2 = (b2 == 2) ? 0 : b2 + 1;
    }

#pragma unroll
    for (int i = 0; i < 4; i++) {
#pragma unroll
        for (int j = 0; j < BSL; j++) {
            int n = bn * BN + wn * (BN / 2) + j * 16 + l15;
#pragma unroll
            for (int r = 0; r < 4; r++) {
                int m = bm * 128 + wm * 64 + i * 16 + quad * 4 + r;
                float fv = acc[i][j][r];
                if (MODE == 1) {
                    outf[(size_t)m * N + n] = fv;
                } else {
                    int t = n >> 10;            // 0=q 1=k 2=v
                    int h = (n >> 6) & 15;
                    int d = n & 63;
                    int b = m >> 11, si = m & 2047;
                    if (t == 2) {
                        // V^T with key interleave within 32-groups
                        int sip = (si & ~31) | (((si >> 2) & 3) << 3)
                                | (((si >> 4) & 1) << 2) | (si & 3);
                        out2[(((size_t)(b * 16 + h)) * 64 + d) * 2048 + sip] = f2bf(fv);
                    } else {
                        // q pre-scaled by 0.125*log2(e) (softmax fold)
                        if (t == 0) fv *= 0.18033688f;
                        size_t off = (((size_t)(b * 16 + h)) * 2048 + si) * 64 + d;
                        unsigned short* dst = (t == 0) ? out0 : out1;
                        dst[off] = f2bf(fv);
                    }
                }
            }
        }
    }
}

// ---------------------------------------------------------------------------
// Flash attention v11 — q-split waves + BLOCK-SHARED staged K/V double-buffer.
// (verified round 7: attn out of top-5, no spills, no bank conflicts)
// q-split: wave owns 16 q-rows, iterates ALL keys -> o[4] accumulator,
// complete per-wave softmax denominator, no cross-wave reduction.
// All 4 waves share one staged 8KB K/V chunk per iter (2 DMAs/wave),
// LDS = 2 x 8KB -> 4 blocks/CU.
// vmcnt(2) per wave: outstanding = stage(t)[2] + mf[2] + stage(t+1)[2];
// waiting to 2 retires stage(t)+mf, keeps stage(t+1) in flight.
//  * full-K=32 PV via key-interleaved V^T (one un-padded MFMA per dt)
//  * mask addend in QK MFMA C-init; Q pre-scaled by 0.125*log2e -> exp2
//    directly on MFMA output.
// ---------------------------------------------------------------------------
__global__ __launch_bounds__(256, 4)
void attn_kernel(const unsigned short* __restrict__ Qb,
                 const unsigned short* __restrict__ Kb,
                 const unsigned short* __restrict__ VbT,
                 const float* __restrict__ m2b,
                 const float* __restrict__ gateb,
                 unsigned short* __restrict__ ctx)
{
    __shared__ unsigned char smem[16384];        // 2 x (K 4KB + V 4KB)
    const int S = 2048;
    const int tid  = threadIdx.x;
    const int wave = tid >> 6, lane = tid & 63;
    const int l15  = lane & 15, quad = lane >> 4;

    int Lid = blockIdx.y * gridDim.x + blockIdx.x;
    int bh = (Lid & 7) * 4 + ((Lid >> 3) & 3);
    int qc = Lid >> 5;
    const int b = bh >> 4, h = bh & 15;
    const int q0 = qc * 64 + wave * 16;          // this wave's 16 q-rows

    const size_t headoff = (size_t)bh * S * 64;
    const unsigned short* Qh  = Qb  + headoff;   // [S][64] (pre-scaled)
    const unsigned short* Kh  = Kb  + headoff;   // [S][64]
    const unsigned short* VhT = VbT + headoff;   // [64][S'] key-interleaved
    const float* m2p = m2b + (size_t)b * S;

    // staging offsets: this wave stages quarter w of each 4KB section
    // (s = wave*64 + lane; K: [32key][64d] swizzled, V: [64d][32k'] swizzled)
    int koff, voff;
    {
        int s = wave * 64 + lane;
        int key = s >> 3;
        koff = key * 64 + (((s & 7) ^ (key & 7)) * 8);
        int d = s >> 2;
        voff = d * 2048 + (((s & 3) ^ (d & 3)) * 8);
    }
    // LDS read offsets (within current buffer)
    int qkoff[2];
#pragma unroll
    for (int s2 = 0; s2 < 2; s2++)
        qkoff[s2] = l15 * 128 + (((s2 * 4 + quad) ^ (l15 & 7)) * 16);
    const int pvoff = 4096 + l15 * 64 + ((quad ^ (l15 & 3)) * 16);

    // Q B-frags for this wave's rows: aq[s2] = Q[q0+l15][s2*32+quad*8+j]
    short8 aq[2];
#pragma unroll
    for (int s2 = 0; s2 < 2; s2++)
        aq[s2] = *(const short8*)(Qh + (size_t)(q0 + l15) * 64 + s2 * 32 + quad * 8);

    floatx4 o[4];                    // O^T partial [dt]  (d = dt*16+quad*4+r)
    floatx4 lq = floatx4{0.f, 0.f, 0.f, 0.f};
#pragma unroll
    for (int dt = 0; dt < 4; dt++) o[dt] = floatx4{0.f, 0.f, 0.f, 0.f};

    const uint4v onesu = {0x3F803F80u, 0x3F803F80u, 0x3F803F80u, 0x3F803F80u};
    const short8 ONES = __builtin_bit_cast(short8, onesu);

    // prologue: stage chunk 0 (keys 0..31) into buffer 0
    gl2lds16(Kh + koff, &smem[wave * 1024]);
    gl2lds16(VhT + voff, &smem[4096 + wave * 1024]);

    for (int i = 0; i < 64; i++) {
        const int cb = (i & 1) * 8192;
        const int nb = ((i + 1) & 1) * 8192;
        const int kb = i * 32;
        // mask addends (QK C-init: C/D row == key == quad*4+r)
        floatx4 mf[2];
#pragma unroll
        for (int t = 0; t < 2; t++)
            mf[t] = *(const floatx4*)(m2p + kb + t * 16 + quad * 4);
        asm volatile("" ::: "memory");
        // barrier 1: all waves done reading buf[nb] (iter i-1)
        __builtin_amdgcn_s_barrier();
        asm volatile("" ::: "memory");
        if (i + 1 < 64) {
            const int kbn = (i + 1) * 32;
            gl2lds16(Kh + (size_t)kbn * 64 + koff, &smem[nb + wave * 1024]);
            gl2lds16(VhT + kbn + voff, &smem[nb + 4096 + wave * 1024]);
            // retire stage(i)+mf (oldest 4); stage(i+1)'s 2 stay in flight
            asm volatile("s_waitcnt vmcnt(2)" ::: "memory");
        } else {
            asm volatile("s_waitcnt vmcnt(0)" ::: "memory");
        }
        // barrier 2: whole chunk i visible to all waves
        __builtin_amdgcn_s_barrier();
        asm volatile("" ::: "memory");

        // K frags from LDS
        short8 kf[2][2];
#pragma unroll
        for (int t = 0; t < 2; t++)
#pragma unroll
            for (int s2 = 0; s2 < 2; s2++)
                kf[t][s2] = *(const short8*)(&smem[cb + qkoff[s2] + t * 2048]);
        // V frags from LDS (interleaved key positions)
        short8 vf[4];
#pragma unroll
        for (int dt = 0; dt < 4; dt++)
            vf[dt] = *(const short8*)(&smem[cb + pvoff + dt * 1024]);

        // S^T = K·Q^T, C init = mask addend (log2 domain, fixed-max -10)
        floatx4 st0 = MFMA32(kf[0][0], aq[0], mf[0]);
        floatx4 st1 = MFMA32(kf[1][0], aq[0], mf[1]);
        st0 = MFMA32(kf[0][1], aq[1], st0);
        st1 = MFMA32(kf[1][1], aq[1], st1);
        // exp directly on MFMA output (Q pre-scaled, mask in C-init)
        float e00 = EXP2(st0[0]), e01 = EXP2(st0[1]);
        float e02 = EXP2(st0[2]), e03 = EXP2(st0[3]);
        float e10 = EXP2(st1[0]), e11 = EXP2(st1[1]);
        float e12 = EXP2(st1[2]), e13 = EXP2(st1[3]);
        // P packed across BOTH key-tiles in interleave order
        uint4v pu = {pack_bf2(e00, e01), pack_bf2(e02, e03),
                     pack_bf2(e10, e11), pack_bf2(e12, e13)};
        short8 pf = __builtin_bit_cast(short8, pu);
        // full-K=32 PV: one un-padded MFMA per dt + one l-row MFMA
#pragma unroll
        for (int dt = 0; dt < 4; dt++)
            o[dt] = MFMA32(vf[dt], pf, o[dt]);
        lq = MFMA32(ONES, pf, lq);
    }

    // epilogue: wave-complete softmax; lane writes q = q0 + l15, d block dt
    float iv = gateb[h] / lq[0];
    size_t base = ((size_t)(b * 2048 + q0 + l15)) * 1024 + h * 64 + quad * 4;
#pragma unroll
    for (int dt = 0; dt < 4; dt++) {
        uint2v w;
        w[0] = pack_bf2(o[dt][0] * iv, o[dt][1] * iv);
        w[1] = pack_bf2(o[dt][2] * iv, o[dt][3] * iv);
        *(uint2v*)(ctx + base + dt * 16) = w;
    }
}

// ---------------------------------------------------------------------------
extern "C" void kernel_launch(void* const* d_in, const int* in_sizes, int n_in,
                              void* d_out, int out_size, void* d_ws, size_t ws_size,
                              hipStream_t stream)
{
    const float* hidden = (const float*)d_in[0]; // [2,2048,1024] fp32
    const float* mask   = (const float*)d_in[1]; // [2,1,1,2048]  fp32
    const float* w_qkv  = (const float*)d_in[2]; // [3072,1024]   fp32
    const float* w_out  = (const float*)d_in[3]; // [1024,1024]   fp32
    const float* gate   = (const float*)d_in[4]; // [16]          fp32
    float* out = (float*)d_out;                  // [2,2048,1024] fp32

    unsigned short* q_buf = (unsigned short*)d_ws;   // [2,16,2048,64] bf16 (pre-scaled)
    unsigned short* k_buf = q_buf + 4194304;         // [2,16,2048,64]
    unsigned short* v_buf = k_buf + 4194304;         // [2,16,64,2048] (V^T, interleaved)
    unsigned short* c_buf = v_buf + 4194304;         // [2,2048,1024]  bf16
    unsigned short* h_bf  = c_buf + 4194304;         // hidden bf16
    unsigned short* wq_bf = h_bf  + 4194304;         // w_qkv bf16
    unsigned short* wo_bf = wq_bf + 3145728;         // w_out bf16
    float* m2_buf = (float*)(wo_bf + 1048576);       // [2,2048] fp32

    // one-pass prep: fp32->bf16 converts + mask transform
    cvt_all<<<8196, 256, 0, stream>>>(hidden, w_qkv, w_out, mask,
                                      h_bf, wq_bf, wo_bf, m2_buf);

    // QKV projection, scatter q(pre-scaled)/k/V^T(interleaved)
    gemm_nt<0, 128><<<dim3(24, 32), 256, 0, stream>>>(h_bf, wq_bf, q_buf, k_buf, v_buf, nullptr, 3072);
    // fused flash attention + gate -> ctx bf16 (64-q blocks, grid 1024)
    attn_kernel<<<dim3(32, 32), 256, 0, stream>>>(q_buf, k_buf, v_buf, m2_buf, gate, c_buf);
    // output projection -> out fp32 (grid 16x32, 128x64 tiles)
    gemm_nt<1, 64><<<dim3(16, 32), 256, 0, stream>>>(c_buf, wo_bf, nullptr, nullptr, nullptr, out, 1024);
}

// Round 9
// 188.304 us; speedup vs baseline: 1.0157x; 1.0157x over previous
//
#include <hip/hip_runtime.h>
#include <stdint.h>

// Problem constants: B=2, S=2048, H=1024, NH=16, HD=64, K=1024
// Inputs FP32 -> one cvt pass to bf16 -> bf16 MFMA pipeline -> output FP32.

typedef __attribute__((ext_vector_type(8))) short short8;
typedef __attribute__((ext_vector_type(4))) float floatx4;
typedef __attribute__((ext_vector_type(4))) unsigned int uint4v;
typedef __attribute__((ext_vector_type(2))) unsigned int uint2v;

__device__ __forceinline__ unsigned short f2bf(float f) {          // RNE
    unsigned int u = __float_as_uint(f);
    unsigned int r = u + 0x7fffu + ((u >> 16) & 1u);
    return (unsigned short)(r >> 16);
}
// pack two fp32 -> bf16x2 dword
#if __has_builtin(__builtin_amdgcn_cvt_pk_bf16_f32)
__device__ __forceinline__ unsigned int pack_bf2(float lo, float hi) {
    auto v = __builtin_amdgcn_cvt_pk_bf16_f32(lo, hi);
    return __builtin_bit_cast(unsigned int, v);
}
#else
__device__ __forceinline__ unsigned int pack_bf2(float lo, float hi) {
    unsigned int a = __float_as_uint(lo) + 0x8000u;
    unsigned int b = __float_as_uint(hi) + 0x8000u;
    return __builtin_amdgcn_perm(b, a, 0x07060302u);
}
#endif

// raw exp2 (v_exp_f32) when available
#if __has_builtin(__builtin_amdgcn_exp2f)
#define EXP2(x) __builtin_amdgcn_exp2f(x)
#else
#define EXP2(x) exp2f(x)
#endif

// async global->LDS, 16B per lane. LDS dest: wave-uniform base + lane*16.
__device__ __forceinline__ void gl2lds16(const void* g, void* l) {
    __builtin_amdgcn_global_load_lds(
        (const __attribute__((address_space(1))) unsigned int*)g,
        (__attribute__((address_space(3))) unsigned int*)l, 16, 0, 0);
}

#define MFMA32(a, b, c) __builtin_amdgcn_mfma_f32_16x16x32_bf16((a), (b), (c), 0, 0, 0)

// ---------------------------------------------------------------------------
// One-pass prep: fp32->bf16 for hidden / w_qkv / w_out, plus mask transform
// m2 = mask*log2(e) - 10*log2(e) (fp32). Grid exactly 8196 x 256.
// ---------------------------------------------------------------------------
__global__ __launch_bounds__(256)
void cvt_all(const float* __restrict__ a, const float* __restrict__ b,
             const float* __restrict__ c, const float* __restrict__ mask,
             unsigned short* __restrict__ oa, unsigned short* __restrict__ ob,
             unsigned short* __restrict__ oc, float* __restrict__ m2b)
{
    int i = blockIdx.x * 256 + threadIdx.x;
    if (i >= 2097152) {                     // mask range: 1024 groups
        int off = i - 2097152;
        float4 v = *(const float4*)(mask + (size_t)off * 4);
        const float L2E = 1.44269504f, C2 = -14.4269504f;
        float4 w;
        w.x = fmaf(v.x, L2E, C2); w.y = fmaf(v.y, L2E, C2);
        w.z = fmaf(v.z, L2E, C2); w.w = fmaf(v.w, L2E, C2);
        *(float4*)(m2b + (size_t)off * 4) = w;
        return;
    }
    const float* src; unsigned short* dst; int off;
    if (i < 1048576)      { src = a; dst = oa; off = i; }
    else if (i < 1835008) { src = b; dst = ob; off = i - 1048576; }
    else                  { src = c; dst = oc; off = i - 1835008; }
    float4 v = *(const float4*)(src + (size_t)off * 4);
    uint2v w;
    w[0] = pack_bf2(v.x, v.y);
    w[1] = pack_bf2(v.z, v.w);
    *(uint2v*)(dst + (size_t)off * 4) = w;
}

// ---------------------------------------------------------------------------
// NT GEMM v3 (verified round 8: gemm_nt left the top-5, was ~75us):
// 128 x BN tile, BK=32, 4 waves (2x2) x (64 x BN/2).
// TRIPLE-buffered LDS + depth-2 prefetch + counted vmcnt; 48KB LDS ->
// 3 blocks/CU, grid 768 fully resident; stage(t) gets ~2 compute phases.
// LDS layout: 128B paired-row lines (2 M-rows x 64B), 8x16B slots XOR-
// swizzled by (line&7) -> 0 measured bank conflicts. Stage side pre-swizzles
// the GLOBAL source address; LDS dest stays linear (gl2lds requirement).
// MODE 0: scatter bf16 to q/k ([B,NH,S,HD]) + V^T ([B,NH,HD,S'])
//         S' key-interleaved within 32-groups:
//         k' = (k&~31) | ((k>>2)&3)<<3 | ((k>>4)&1)<<2 | (k&3).
//         q PRE-SCALED by 0.125*log2(e) so attn exp2's the raw MFMA out.
// MODE 1: fp32 store outf[m*N+n].
// ---------------------------------------------------------------------------
template<int MODE, int BN>
__global__ __launch_bounds__(256)
void gemm_nt(const unsigned short* __restrict__ A,
             const unsigned short* __restrict__ Bm,
             unsigned short* __restrict__ out0,
             unsigned short* __restrict__ out1,
             unsigned short* __restrict__ out2,
             float* __restrict__ outf,
             int N)
{
    constexpr int BUFB  = 8192 + BN * 64;        // bytes per buffer (A + B)
    constexpr int NSTEP = 32;                    // K / 32
    constexpr int NA    = 2;                     // A DMAs per wave per stage
    constexpr int NB    = BN / 64;               // B DMAs per wave per stage
    constexpr int BSL   = BN / 32;
    __shared__ unsigned char smem[3 * BUFB];
    const int K = 1024;
    const int tid  = threadIdx.x;
    const int wave = tid >> 6, lane = tid & 63;
    const int l15  = lane & 15, quad = lane >> 4;
    const int wm = wave >> 1, wn = wave & 1;

    int Lid = blockIdx.y * gridDim.x + blockIdx.x;
    int bm = (Lid & 7) * 4 + ((Lid >> 3) & 3);
    int bn = Lid >> 5;

    floatx4 acc[4][BSL];
#pragma unroll
    for (int i = 0; i < 4; i++)
#pragma unroll
        for (int j = 0; j < BSL; j++)
            acc[i][j] = floatx4{0.f, 0.f, 0.f, 0.f};

    // staging maps: chunk s (16B units) -> LDS line L = s>>3, slot p = s&7.
    // content q = p ^ (L&7): global (Mrow = L*2 + (q>>2), Kblk = q&3).
    int soffA[NA], soffB[NB];
#pragma unroll
    for (int l = 0; l < NA; l++) {
        int s = (wave * NA + l) * 64 + lane;
        int L = s >> 3, q = (s & 7) ^ (L & 7);
        soffA[l] = (L * 2 + (q >> 2)) * K + (q & 3) * 8;
    }
#pragma unroll
    for (int l = 0; l < NB; l++) {
        int s = (wave * NB + l) * 64 + lane;
        int L = s >> 3, q = (s & 7) ^ (L & 7);
        soffB[l] = (L * 2 + (q >> 2)) * K + (q & 3) * 8;
    }
    // read maps: row r, K-block quad -> line r>>1, slot (((r&1)<<2)|quad)^(line&7)
    int aoff[4], boff[BSL];
#pragma unroll
    for (int i = 0; i < 4; i++) {
        int r = wm * 64 + i * 16 + l15, L = r >> 1;
        aoff[i] = L * 128 + (((((r & 1) << 2) | quad) ^ (L & 7)) * 16);
    }
#pragma unroll
    for (int j = 0; j < BSL; j++) {
        int r = wn * (BN / 2) + j * 16 + l15, L = r >> 1;
        boff[j] = 8192 + L * 128 + (((((r & 1) << 2) | quad) ^ (L & 7)) * 16);
    }

    const unsigned short* Abase = A  + (size_t)(bm * 128) * K;
    const unsigned short* Bbase = Bm + (size_t)(bn * BN) * K;

    auto STAGE = [&](int u, int bufb) {
        const int k0 = u * 32;
#pragma unroll
        for (int l = 0; l < NA; l++)
            gl2lds16(Abase + (size_t)soffA[l] + k0, &smem[bufb + (wave * NA + l) * 1024]);
#pragma unroll
        for (int l = 0; l < NB; l++)
            gl2lds16(Bbase + (size_t)soffB[l] + k0, &smem[bufb + 8192 + (wave * NB + l) * 1024]);
    };

    // prologue: stages 0,1 into buffers 0,1
    STAGE(0, 0);
    STAGE(1, BUFB);

    int b0 = 0, b2 = 2;                          // compute buf, stage buf
    for (int t = 0; t < NSTEP; t++) {
        // barrier 1: all waves done computing step t-1 -> buf[b2] reusable
        asm volatile("" ::: "memory");
        __builtin_amdgcn_s_barrier();
        asm volatile("" ::: "memory");
        if (t + 2 < NSTEP) {
            STAGE(t + 2, b2 * BUFB);
            // retire stage(t); stages t+1,t+2 (2*NDMA) stay in flight
            if (BN == 128) asm volatile("s_waitcnt vmcnt(8)" ::: "memory");
            else           asm volatile("s_waitcnt vmcnt(6)" ::: "memory");
        } else if (t + 2 == NSTEP) {
            if (BN == 128) asm volatile("s_waitcnt vmcnt(4)" ::: "memory");
            else           asm volatile("s_waitcnt vmcnt(3)" ::: "memory");
        } else {
            asm volatile("s_waitcnt vmcnt(0)" ::: "memory");
        }
        // barrier 2: tile t visible block-wide
        __builtin_amdgcn_s_barrier();
        asm volatile("" ::: "memory");

        const int cb = b0 * BUFB;
        short8 af[4], bfr[BSL];
#pragma unroll
        for (int i = 0; i < 4; i++)
            af[i] = *(const short8*)(&smem[cb + aoff[i]]);
#pragma unroll
        for (int j = 0; j < BSL; j++)
            bfr[j] = *(const short8*)(&smem[cb + boff[j]]);
#pragma unroll
        for (int i = 0; i < 4; i++)
#pragma unroll
            for (int j = 0; j < BSL; j++)
                acc[i][j] = MFMA32(af[i], bfr[j], acc[i][j]);

        b0 = (b0 == 2) ? 0 : b0 + 1;
        b2 = (b2 == 2) ? 0 : b2 + 1;
    }

#pragma unroll
    for (int i = 0; i < 4; i++) {
#pragma unroll
        for (int j = 0; j < BSL; j++) {
            int n = bn * BN + wn * (BN / 2) + j * 16 + l15;
#pragma unroll
            for (int r = 0; r < 4; r++) {
                int m = bm * 128 + wm * 64 + i * 16 + quad * 4 + r;
                float fv = acc[i][j][r];
                if (MODE == 1) {
                    outf[(size_t)m * N + n] = fv;
                } else {
                    int t = n >> 10;            // 0=q 1=k 2=v
                    int h = (n >> 6) & 15;
                    int d = n & 63;
                    int b = m >> 11, si = m & 2047;
                    if (t == 2) {
                        // V^T with key interleave within 32-groups
                        int sip = (si & ~31) | (((si >> 2) & 3) << 3)
                                | (((si >> 4) & 1) << 2) | (si & 3);
                        out2[(((size_t)(b * 16 + h)) * 64 + d) * 2048 + sip] = f2bf(fv);
                    } else {
                        // q pre-scaled by 0.125*log2(e) (softmax fold)
                        if (t == 0) fv *= 0.18033688f;
                        size_t off = (((size_t)(b * 16 + h)) * 2048 + si) * 64 + d;
                        unsigned short* dst = (t == 0) ? out0 : out1;
                        dst[off] = f2bf(fv);
                    }
                }
            }
        }
    }
}

// ---------------------------------------------------------------------------
// Flash attention v12 — v11 + two LDS-BW fixes (round-8 PMC: attn is LDS-BW
// bound: 2.1GB LDS reads ~30us floor + 4.19M bank conflicts; dur 53.5us).
// (1) V tile re-shaped to 128B PAIRED-ROW lines with 8-slot XOR swizzle —
//     the exact geometry the gemm A-tile uses, which measures 0 conflicts.
//     Old V layout (64B rows, 2-bit XOR) was ~4-way conflicted (the 4.19M).
//     line L = d>>1; slot p holds content q = p^(L&7); q = (d&1)*4 + kslot.
// (2) 32 q-rows per wave (2 sub-tiles): the same 8 ds_read_b128 per iter
//     now feed 18 MFMAs instead of 9 -> total LDS traffic HALVES (1.05GB,
//     ~14us floor). Grid 512 (2 blocks/CU, zero tail), (256,2) so the
//     ~120-VGPR live set has headroom (round-2 spill lesson).
// Everything else verified in round 7/8: q-split wave-complete softmax (no
// cross-wave reduction), block-shared staged K/V double-buffer with raw
// barriers + vmcnt(2), full-K=32 PV via key-interleaved V^T, mask addend in
// QK C-init, Q pre-scaled by 0.125*log2e -> exp2 on raw MFMA output.
// ---------------------------------------------------------------------------
__global__ __launch_bounds__(256, 2)
void attn_kernel(const unsigned short* __restrict__ Qb,
                 const unsigned short* __restrict__ Kb,
                 const unsigned short* __restrict__ VbT,
                 const float* __restrict__ m2b,
                 const float* __restrict__ gateb,
                 unsigned short* __restrict__ ctx)
{
    __shared__ unsigned char smem[16384];        // 2 x (K 4KB + V 4KB)
    const int S = 2048;
    const int tid  = threadIdx.x;
    const int wave = tid >> 6, lane = tid & 63;
    const int l15  = lane & 15, quad = lane >> 4;

    int Lid = blockIdx.y * gridDim.x + blockIdx.x;
    int bh = (Lid & 7) * 4 + ((Lid >> 3) & 3);
    int qc = Lid >> 5;                           // 0..15 (128 q-rows/block)
    const int b = bh >> 4, h = bh & 15;
    const int q0 = qc * 128 + wave * 32;         // this wave's 32 q-rows

    const size_t headoff = (size_t)bh * S * 64;
    const unsigned short* Qh  = Qb  + headoff;   // [S][64] (pre-scaled)
    const unsigned short* Kh  = Kb  + headoff;   // [S][64]
    const unsigned short* VhT = VbT + headoff;   // [64][S'] key-interleaved
    const float* m2p = m2b + (size_t)b * S;

    // staging offsets (s = wave*64 + lane, 16B units):
    // K section: [32key][64d], row-swizzled (verified 0-conflict on reads).
    // V section: paired-row lines — L = s>>3, p = s&7, content q = p^(L&7),
    //            global (d = L*2 + q>>2, kslot = q&3).
    int koff, voff;
    {
        int s = wave * 64 + lane;
        int key = s >> 3;
        koff = key * 64 + (((s & 7) ^ (key & 7)) * 8);
        int L = s >> 3, q = (s & 7) ^ (L & 7);
        voff = (L * 2 + (q >> 2)) * 2048 + (q & 3) * 8;
    }
    // LDS read offsets (within current buffer)
    int qkoff[2];
#pragma unroll
    for (int s2 = 0; s2 < 2; s2++)
        qkoff[s2] = l15 * 128 + (((s2 * 4 + quad) ^ (l15 & 7)) * 16);
    // vf[dt]: d = dt*16 + l15, kslot = quad -> line dt*8 + (l15>>1),
    // slot (((l15&1)<<2)|quad) ^ ((l15>>1)&7)   [dt*8 = 0 mod 8]
    const int pvoff = 4096 + (l15 >> 1) * 128
                    + (((((l15 & 1) << 2) | quad) ^ ((l15 >> 1) & 7)) * 16);

    // Q B-frags: aq[sub][s2] = Q[q0+sub*16+l15][s2*32+quad*8+j]
    short8 aq[2][2];
#pragma unroll
    for (int sub = 0; sub < 2; sub++)
#pragma unroll
        for (int s2 = 0; s2 < 2; s2++)
            aq[sub][s2] = *(const short8*)(Qh + (size_t)(q0 + sub * 16 + l15) * 64 + s2 * 32 + quad * 8);

    floatx4 o[2][4];                 // O^T partial [sub][dt]
    floatx4 lq[2];                   // l partial [sub]
#pragma unroll
    for (int sub = 0; sub < 2; sub++) {
        lq[sub] = floatx4{0.f, 0.f, 0.f, 0.f};
#pragma unroll
        for (int dt = 0; dt < 4; dt++) o[sub][dt] = floatx4{0.f, 0.f, 0.f, 0.f};
    }

    const uint4v onesu = {0x3F803F80u, 0x3F803F80u, 0x3F803F80u, 0x3F803F80u};
    const short8 ONES = __builtin_bit_cast(short8, onesu);

    // prologue: stage chunk 0 (keys 0..31) into buffer 0
    gl2lds16(Kh + koff, &smem[wave * 1024]);
    gl2lds16(VhT + voff, &smem[4096 + wave * 1024]);

    for (int i = 0; i < 64; i++) {
        const int cb = (i & 1) * 8192;
        const int nb = ((i + 1) & 1) * 8192;
        const int kb = i * 32;
        // mask addends (QK C-init: C/D row == key == quad*4+r)
        floatx4 mf[2];
#pragma unroll
        for (int t = 0; t < 2; t++)
            mf[t] = *(const floatx4*)(m2p + kb + t * 16 + quad * 4);
        asm volatile("" ::: "memory");
        // barrier 1: all waves done reading buf[nb] (iter i-1)
        __builtin_amdgcn_s_barrier();
        asm volatile("" ::: "memory");
        if (i + 1 < 64) {
            const int kbn = (i + 1) * 32;
            gl2lds16(Kh + (size_t)kbn * 64 + koff, &smem[nb + wave * 1024]);
            gl2lds16(VhT + kbn + voff, &smem[nb + 4096 + wave * 1024]);
            // retire stage(i)+mf (oldest 4); stage(i+1)'s 2 stay in flight
            asm volatile("s_waitcnt vmcnt(2)" ::: "memory");
        } else {
            asm volatile("s_waitcnt vmcnt(0)" ::: "memory");
        }
        // barrier 2: whole chunk i visible to all waves
        __builtin_amdgcn_s_barrier();
        asm volatile("" ::: "memory");

        // K frags from LDS
        short8 kf[2][2];
#pragma unroll
        for (int t = 0; t < 2; t++)
#pragma unroll
            for (int s2 = 0; s2 < 2; s2++)
                kf[t][s2] = *(const short8*)(&smem[cb + qkoff[s2] + t * 2048]);
        // V frags from LDS (paired-line swizzle, interleaved key positions)
        short8 vf[4];
#pragma unroll
        for (int dt = 0; dt < 4; dt++)
            vf[dt] = *(const short8*)(&smem[cb + pvoff + dt * 1024]);

#pragma unroll
        for (int sub = 0; sub < 2; sub++) {
            // S^T = K·Q^T, C init = mask addend (log2 domain, fixed-max -10)
            floatx4 st0 = MFMA32(kf[0][0], aq[sub][0], mf[0]);
            floatx4 st1 = MFMA32(kf[1][0], aq[sub][0], mf[1]);
            st0 = MFMA32(kf[0][1], aq[sub][1], st0);
            st1 = MFMA32(kf[1][1], aq[sub][1], st1);
            // exp directly on MFMA output (Q pre-scaled, mask in C-init)
            float e00 = EXP2(st0[0]), e01 = EXP2(st0[1]);
            float e02 = EXP2(st0[2]), e03 = EXP2(st0[3]);
            float e10 = EXP2(st1[0]), e11 = EXP2(st1[1]);
            float e12 = EXP2(st1[2]), e13 = EXP2(st1[3]);
            // P packed across BOTH key-tiles in interleave order
            uint4v pu = {pack_bf2(e00, e01), pack_bf2(e02, e03),
                         pack_bf2(e10, e11), pack_bf2(e12, e13)};
            short8 pf = __builtin_bit_cast(short8, pu);
            // full-K=32 PV: one un-padded MFMA per dt + one l-row MFMA
#pragma unroll
            for (int dt = 0; dt < 4; dt++)
                o[sub][dt] = MFMA32(vf[dt], pf, o[sub][dt]);
            lq[sub] = MFMA32(ONES, pf, lq[sub]);
        }
    }

    // epilogue: wave-complete softmax; lane writes q = q0+sub*16+l15, all dt
    float g = gateb[h];
#pragma unroll
    for (int sub = 0; sub < 2; sub++) {
        float iv = g / lq[sub][0];
        size_t base = ((size_t)(b * 2048 + q0 + sub * 16 + l15)) * 1024 + h * 64 + quad * 4;
#pragma unroll
        for (int dt = 0; dt < 4; dt++) {
            uint2v w;
            w[0] = pack_bf2(o[sub][dt][0] * iv, o[sub][dt][1] * iv);
            w[1] = pack_bf2(o[sub][dt][2] * iv, o[sub][dt][3] * iv);
            *(uint2v*)(ctx + base + dt * 16) = w;
        }
    }
}

// ---------------------------------------------------------------------------
extern "C" void kernel_launch(void* const* d_in, const int* in_sizes, int n_in,
                              void* d_out, int out_size, void* d_ws, size_t ws_size,
                              hipStream_t stream)
{
    const float* hidden = (const float*)d_in[0]; // [2,2048,1024] fp32
    const float* mask   = (const float*)d_in[1]; // [2,1,1,2048]  fp32
    const float* w_qkv  = (const float*)d_in[2]; // [3072,1024]   fp32
    const float* w_out  = (const float*)d_in[3]; // [1024,1024]   fp32
    const float* gate   = (const float*)d_in[4]; // [16]          fp32
    float* out = (float*)d_out;                  // [2,2048,1024] fp32

    unsigned short* q_buf = (unsigned short*)d_ws;   // [2,16,2048,64] bf16 (pre-scaled)
    unsigned short* k_buf = q_buf + 4194304;         // [2,16,2048,64]
    unsigned short* v_buf = k_buf + 4194304;         // [2,16,64,2048] (V^T, interleaved)
    unsigned short* c_buf = v_buf + 4194304;         // [2,2048,1024]  bf16
    unsigned short* h_bf  = c_buf + 4194304;         // hidden bf16
    unsigned short* wq_bf = h_bf  + 4194304;         // w_qkv bf16
    unsigned short* wo_bf = wq_bf + 3145728;         // w_out bf16
    float* m2_buf = (float*)(wo_bf + 1048576);       // [2,2048] fp32

    // one-pass prep: fp32->bf16 converts + mask transform
    cvt_all<<<8196, 256, 0, stream>>>(hidden, w_qkv, w_out, mask,
                                      h_bf, wq_bf, wo_bf, m2_buf);

    // QKV projection, scatter q(pre-scaled)/k/V^T(interleaved)
    gemm_nt<0, 128><<<dim3(24, 32), 256, 0, stream>>>(h_bf, wq_bf, q_buf, k_buf, v_buf, nullptr, 3072);
    // fused flash attention + gate -> ctx bf16 (128-q blocks, grid 512)
    attn_kernel<<<dim3(16, 32), 256, 0, stream>>>(q_buf, k_buf, v_buf, m2_buf, gate, c_buf);
    // output projection -> out fp32 (grid 16x32, 128x64 tiles)
    gemm_nt<1, 64><<<dim3(16, 32), 256, 0, stream>>>(c_buf, wo_bf, nullptr, nullptr, nullptr, out, 1024);
}